// Round 4
// baseline (245.152 us; speedup 1.0000x reference)
//
#include <hip/hip_runtime.h>
#include <math.h>

// (B,C,H,W)=(8,256,64,64); NH=NP=4, d=64, Nq=4096, M=B*Nq=32768.
namespace {
constexpr int kC = 256;
constexpr int kNq = 4096;
constexpr int kM = 32768;
}

typedef __attribute__((ext_vector_type(8))) short short8;
typedef __attribute__((ext_vector_type(4))) float f32x4;

__device__ inline unsigned short f2bf(float f) {
  union { float f; unsigned u; } v; v.f = f;
  unsigned r = (v.u + 0x7FFFu + ((v.u >> 16) & 1u)) >> 16;  // RNE
  return (unsigned short)r;
}
__device__ inline float uasf(unsigned u) {
  union { unsigned u; float f; } v; v.u = u; return v.f;
}

// -----------------------------------------------------------------------------
// K0: weight prep — bf16 + transpose so MFMA operands are row-major in K.
// -----------------------------------------------------------------------------
__global__ __launch_bounds__(256)
void prep_weights_kernel(const float* __restrict__ Wv, const float* __restrict__ Wo,
                         const float* __restrict__ Woff, const float* __restrict__ Watt,
                         unsigned short* __restrict__ WvT, unsigned short* __restrict__ WoT,
                         unsigned short* __restrict__ WoaT) {
  const int i = blockIdx.x * 256 + threadIdx.x;  // 256 blocks -> i < 65536
  {
    const int n = i >> 8, k = i & 255;
    WvT[i] = f2bf(Wv[k * 256 + n]);
    WoT[i] = f2bf(Wo[k * 256 + n]);
  }
  if (i < 16384) {
    const int j = i >> 8, k = i & 255;
    float v = 0.f;
    if (j < 32) v = Woff[k * 32 + j];
    else if (j < 48) v = Watt[k * 16 + (j - 32)];
    WoaT[i] = f2bf(v);
  }
}

// -----------------------------------------------------------------------------
// Fused LN(+qpos)+transpose+GEMM helper structure:
// Block = 128 queries of one batch. Phase A: 4 groups of 32 queries are staged
// through an fp32 LDS scratch (overlaid on Bs), per-query mean/rstd computed,
// normalized bf16 written into As[128][264]. Phase B: B-tile(s) loaded into Bs,
// full-K=256 MFMA GEMM from LDS. LDS ~138 KB -> 1 block/CU (4 waves), but the
// kernel is HBM-bound on its compulsory x-read.
// Frag layouts [guide §3]: A/B lane = [idx = lane&15][k = quad*8+j];
// C/D: col = lane&15, row = quad*4 + reg.
// -----------------------------------------------------------------------------

// K1: V = LN2(x2^T) @ W_val + b_val   (bf16 out)
__global__ __launch_bounds__(256)
void fused_val_kernel(const float* __restrict__ X, const float* __restrict__ gam,
                      const float* __restrict__ beta, const unsigned short* __restrict__ Bt,
                      const float* __restrict__ bias, unsigned short* __restrict__ V) {
  __shared__ unsigned short As[128][264];   // 67584 B
  __shared__ unsigned short Bs[128][264];   // 67584 B (phase-A scratch overlay)
  __shared__ float psum[8][32];
  __shared__ float psq[8][32];
  __shared__ float smean[128];
  __shared__ float srstd[128];
  float* scratch = (float*)&Bs[0][0];       // [256][33] fp32 = 33792 B

  const int m0 = blockIdx.x * 128;
  const int b = m0 >> 12;
  const int n0 = m0 & 4095;
  const int tid = threadIdx.x;
  const float gc = gam[tid];
  const float bc = beta[tid];
  const float* Xb = X + (size_t)b * kC * kNq;

  for (int grp = 0; grp < 4; ++grp) {
    for (int i = tid; i < 256 * 32; i += 256) {
      const int c = i >> 5, nn = i & 31;
      scratch[c * 33 + nn] = Xb[(size_t)c * kNq + n0 + grp * 32 + nn];
    }
    __syncthreads();
    {
      const int nn = tid & 31, cg = tid >> 5;
      float s = 0.f, sq = 0.f;
#pragma unroll
      for (int cc = 0; cc < 32; ++cc) {
        const float v = scratch[(cg * 32 + cc) * 33 + nn];
        s += v; sq += v * v;
      }
      psum[cg][nn] = s; psq[cg][nn] = sq;
    }
    __syncthreads();
    if (tid < 32) {
      float S = 0.f, Q = 0.f;
#pragma unroll
      for (int g = 0; g < 8; ++g) { S += psum[g][tid]; Q += psq[g][tid]; }
      const float m = S * (1.f / 256.f);
      const float v = Q * (1.f / 256.f) - m * m;
      smean[grp * 32 + tid] = m;
      srstd[grp * 32 + tid] = rsqrtf(v + 1e-5f);
    }
    __syncthreads();
    // normalize: thread = channel c (=tid); scratch read (tid+q)%32 banks: free
    for (int q = 0; q < 32; ++q) {
      const int row = grp * 32 + q;
      As[row][tid] = f2bf((scratch[tid * 33 + q] - smean[row]) * srstd[row] * gc + bc);
    }
    __syncthreads();
  }

  const int lane = tid & 63, w = tid >> 6;
  const int wm = w >> 1, wn = w & 1;
  const int l15 = lane & 15, quad = lane >> 4;

  for (int nh = 0; nh < 2; ++nh) {
    for (int i = tid; i < 4096; i += 256) {  // 128 rows x 32 short8
      const int r = i >> 5, cc = (i & 31) * 8;
      *(short8*)&Bs[r][cc] = *(const short8*)&Bt[(size_t)(nh * 128 + r) * 256 + cc];
    }
    __syncthreads();
    f32x4 acc[4][4];
#pragma unroll
    for (int i = 0; i < 4; ++i)
#pragma unroll
      for (int j = 0; j < 4; ++j) acc[i][j] = (f32x4){0.f, 0.f, 0.f, 0.f};
#pragma unroll
    for (int s = 0; s < 8; ++s) {
      short8 af[4], bfr[4];
#pragma unroll
      for (int t = 0; t < 4; ++t) af[t] = *(const short8*)&As[wm * 64 + t * 16 + l15][s * 32 + quad * 8];
#pragma unroll
      for (int t = 0; t < 4; ++t) bfr[t] = *(const short8*)&Bs[wn * 64 + t * 16 + l15][s * 32 + quad * 8];
#pragma unroll
      for (int i = 0; i < 4; ++i)
#pragma unroll
        for (int j = 0; j < 4; ++j)
          acc[i][j] = __builtin_amdgcn_mfma_f32_16x16x32_bf16(af[i], bfr[j], acc[i][j], 0, 0, 0);
    }
#pragma unroll
    for (int i = 0; i < 4; ++i)
#pragma unroll
      for (int j = 0; j < 4; ++j) {
        const int n = nh * 128 + wn * 64 + j * 16 + l15;
        const float bn = bias[n];
#pragma unroll
        for (int r = 0; r < 4; ++r) {
          const int m = m0 + wm * 64 + i * 16 + quad * 4 + r;
          V[(size_t)m * 256 + n] = f2bf(acc[i][j][r] + bn);
        }
      }
    __syncthreads();  // protect Bs before next-half reload
  }
}

// K2: RAW = (LN1(x1^T)+qpos) @ [W_off|W_att] + bias   (128x64 tile, N=48 live)
__global__ __launch_bounds__(256)
void fused_offatt_kernel(const float* __restrict__ X, const float* __restrict__ gam,
                         const float* __restrict__ beta, const float* __restrict__ ps,
                         const unsigned short* __restrict__ Wt,  // [64][256] WoaT
                         const float* __restrict__ boff, const float* __restrict__ batt,
                         float* __restrict__ RAW) {
  __shared__ unsigned short As[128][264];   // 67584 B
  __shared__ unsigned short Bs[64][264];    // 33792 B (== scratch size exactly)
  __shared__ float psum[8][32];
  __shared__ float psq[8][32];
  __shared__ float smean[128];
  __shared__ float srstd[128];
  float* scratch = (float*)&Bs[0][0];       // [256][33] fp32 = 33792 B

  const int m0 = blockIdx.x * 128;
  const int b = m0 >> 12;
  const int n0 = m0 & 4095;
  const int tid = threadIdx.x;
  const float gc = gam[tid];
  const float bc = beta[tid];
  const float scale = ps[0];
  const int i2 = (tid < 128) ? tid : (tid - 128);
  const float invf = powf(10000.f, -(float)(2 * i2) * (1.f / 256.f));
  const float* Xb = X + (size_t)b * kC * kNq;

  for (int grp = 0; grp < 4; ++grp) {
    for (int i = tid; i < 256 * 32; i += 256) {
      const int c = i >> 5, nn = i & 31;
      scratch[c * 33 + nn] = Xb[(size_t)c * kNq + n0 + grp * 32 + nn];
    }
    __syncthreads();
    {
      const int nn = tid & 31, cg = tid >> 5;
      float s = 0.f, sq = 0.f;
#pragma unroll
      for (int cc = 0; cc < 32; ++cc) {
        const float v = scratch[(cg * 32 + cc) * 33 + nn];
        s += v; sq += v * v;
      }
      psum[cg][nn] = s; psq[cg][nn] = sq;
    }
    __syncthreads();
    if (tid < 32) {
      float S = 0.f, Q = 0.f;
#pragma unroll
      for (int g = 0; g < 8; ++g) { S += psum[g][tid]; Q += psq[g][tid]; }
      const float m = S * (1.f / 256.f);
      const float v = Q * (1.f / 256.f) - m * m;
      smean[grp * 32 + tid] = m;
      srstd[grp * 32 + tid] = rsqrtf(v + 1e-5f);
    }
    __syncthreads();
    for (int q = 0; q < 32; ++q) {
      const int row = grp * 32 + q;
      float val = (scratch[tid * 33 + q] - smean[row]) * srstd[row] * gc + bc;
      const float a = (float)(n0 + row) * invf;
      val += ((tid < 128) ? sinf(a) : cosf(a)) * scale;
      As[row][tid] = f2bf(val);
    }
    __syncthreads();
  }

  const int lane = tid & 63, w = tid >> 6;
  const int wm = w >> 1, wn = w & 1;   // wave: 64 q x 32 n
  const int l15 = lane & 15, quad = lane >> 4;

  for (int i = tid; i < 2048; i += 256) {  // 64 rows x 32 short8
    const int r = i >> 5, cc = (i & 31) * 8;
    *(short8*)&Bs[r][cc] = *(const short8*)&Wt[(size_t)r * 256 + cc];
  }
  __syncthreads();
  f32x4 acc[4][2];
#pragma unroll
  for (int i = 0; i < 4; ++i) { acc[i][0] = (f32x4){0.f,0.f,0.f,0.f}; acc[i][1] = (f32x4){0.f,0.f,0.f,0.f}; }
#pragma unroll
  for (int s = 0; s < 8; ++s) {
    short8 af[4], bfr[2];
#pragma unroll
    for (int t = 0; t < 4; ++t) af[t] = *(const short8*)&As[wm * 64 + t * 16 + l15][s * 32 + quad * 8];
#pragma unroll
    for (int t = 0; t < 2; ++t) bfr[t] = *(const short8*)&Bs[wn * 32 + t * 16 + l15][s * 32 + quad * 8];
#pragma unroll
    for (int i = 0; i < 4; ++i)
#pragma unroll
      for (int j = 0; j < 2; ++j)
        acc[i][j] = __builtin_amdgcn_mfma_f32_16x16x32_bf16(af[i], bfr[j], acc[i][j], 0, 0, 0);
  }
#pragma unroll
  for (int i = 0; i < 4; ++i)
#pragma unroll
    for (int j = 0; j < 2; ++j) {
      const int n = wn * 32 + j * 16 + l15;
      if (n < 48) {
        const float bn = (n < 32) ? boff[n] : batt[n - 32];
#pragma unroll
        for (int r = 0; r < 4; ++r) {
          const int m = m0 + wm * 64 + i * 16 + quad * 4 + r;
          RAW[(size_t)m * 48 + n] = acc[i][j][r] + bn;
        }
      }
    }
}

// -----------------------------------------------------------------------------
// K3: two-phase sampling (round-3 structure) + XCD-aware swizzle: batch =
// blockIdx&7 so each XCD's L2 caches exactly one batch's 2 MB V-slice.
// -----------------------------------------------------------------------------
__global__ __launch_bounds__(256)
void sample_kernel(const float* __restrict__ RAW, const unsigned short* __restrict__ V,
                   unsigned short* __restrict__ AO) {
  __shared__ int sidx[128][4];
  __shared__ float swgt[128][4];
  const int blk = blockIdx.x;
  const int m0 = ((blk & 7) * 512 + (blk >> 3)) * 8;   // batch = blk & 7
  const int b = m0 >> 12;
  const int tid = threadIdx.x;

  if (tid < 128) {
    const int q_l = tid >> 4, h = (tid >> 2) & 3, p = tid & 3;
    const int m = m0 + q_l;
    const float* raw = RAW + (size_t)m * 48;
    const float l0 = raw[32 + h * 4 + 0];
    const float l1 = raw[32 + h * 4 + 1];
    const float l2 = raw[32 + h * 4 + 2];
    const float l3 = raw[32 + h * 4 + 3];
    const float mx = fmaxf(fmaxf(l0, l1), fmaxf(l2, l3));
    const float e0 = expf(l0 - mx), e1 = expf(l1 - mx), e2 = expf(l2 - mx), e3 = expf(l3 - mx);
    const float lp = (p == 0) ? e0 : (p == 1) ? e1 : (p == 2) ? e2 : e3;
    const float attp = lp / (e0 + e1 + e2 + e3);

    const float ox = raw[h * 8 + p * 2 + 0];
    const float oy = raw[h * 8 + p * 2 + 1];
    const float px = (float)(m & 63) + ox;        // W=64 cancels the normalizer
    const float py = (float)((m >> 6) & 63) + oy;
    const float fx = floorf(px), fy = floorf(py);
    const float wx = px - fx, wy = py - fy;
    const int x0 = (int)fx, y0 = (int)fy;
#pragma unroll
    for (int c = 0; c < 4; ++c) {
      const int dx = c & 1, dy = c >> 1;
      const int xx = x0 + dx, yy = y0 + dy;
      const bool valid = (xx >= 0) & (xx < 64) & (yy >= 0) & (yy < 64);
      const float wc = (dx ? wx : 1.f - wx) * (dy ? wy : 1.f - wy) * attp;
      swgt[tid][c] = valid ? wc : 0.f;
      const int xc = min(max(xx, 0), 63), yc = min(max(yy, 0), 63);
      sidx[tid][c] = yc * 64 + xc;
    }
  }
  __syncthreads();

  const int q_l = tid >> 5, sub = tid & 31;
  const int h = sub >> 3, c8 = (sub & 7) * 8;
  const int trip0 = q_l * 16 + h * 4;
  const unsigned short* vb = V + (size_t)b * kNq * kC + h * 64 + c8;
  float acc[8] = {};
#pragma unroll
  for (int p = 0; p < 4; ++p) {
    const int4 idx = *(const int4*)&sidx[trip0 + p][0];
    const float4 wv = *(const float4*)&swgt[trip0 + p][0];
    const int ia[4] = {idx.x, idx.y, idx.z, idx.w};
    const float wa[4] = {wv.x, wv.y, wv.z, wv.w};
#pragma unroll
    for (int c = 0; c < 4; ++c) {
      const uint4 u = *(const uint4*)&vb[(size_t)ia[c] * kC];
      const float w = wa[c];
      acc[0] = fmaf(w, uasf(u.x << 16), acc[0]);
      acc[1] = fmaf(w, uasf(u.x & 0xffff0000u), acc[1]);
      acc[2] = fmaf(w, uasf(u.y << 16), acc[2]);
      acc[3] = fmaf(w, uasf(u.y & 0xffff0000u), acc[3]);
      acc[4] = fmaf(w, uasf(u.z << 16), acc[4]);
      acc[5] = fmaf(w, uasf(u.z & 0xffff0000u), acc[5]);
      acc[6] = fmaf(w, uasf(u.w << 16), acc[6]);
      acc[7] = fmaf(w, uasf(u.w & 0xffff0000u), acc[7]);
    }
  }
  const int m = m0 + q_l;
  short8 outv;
#pragma unroll
  for (int e = 0; e < 8; ++e) outv[e] = (short)f2bf(acc[e]);
  *(short8*)&AO[(size_t)m * kC + h * 64 + c8] = outv;
}

// -----------------------------------------------------------------------------
// K4: out-projection transposed: D[c][q] = WoT[c][:] . AO[q][:]; AO tile (Bs)
// loaded ONCE, WoT streamed in two c-halves. Store contiguous in q + residual.
// -----------------------------------------------------------------------------
__global__ __launch_bounds__(256)
void gemm_out_kernel(const unsigned short* __restrict__ Wt,  // [256][256] WoT
                     const unsigned short* __restrict__ AO,  // [kM][256] bf16
                     const float* __restrict__ bias, const float* __restrict__ x2,
                     float* __restrict__ OUT) {
  __shared__ unsigned short As[128][264];  // WoT c-half
  __shared__ unsigned short Bs[128][264];  // AO rows (q)
  const int q0 = blockIdx.x * 128;
  const int tid = threadIdx.x;
  const int lane = tid & 63, w = tid >> 6;
  const int wm = w >> 1, wn = w & 1;
  const int l15 = lane & 15, quad = lane >> 4;

  for (int i = tid; i < 4096; i += 256) {
    const int r = i >> 5, cc = (i & 31) * 8;
    *(short8*)&Bs[r][cc] = *(const short8*)&AO[(size_t)(q0 + r) * 256 + cc];
  }

  const int b = q0 >> 12;
  const int qb = q0 & 4095;

  for (int ch = 0; ch < 2; ++ch) {
    for (int i = tid; i < 4096; i += 256) {
      const int r = i >> 5, cc = (i & 31) * 8;
      *(short8*)&As[r][cc] = *(const short8*)&Wt[(size_t)(ch * 128 + r) * 256 + cc];
    }
    __syncthreads();
    f32x4 acc[4][4];
#pragma unroll
    for (int i = 0; i < 4; ++i)
#pragma unroll
      for (int j = 0; j < 4; ++j) acc[i][j] = (f32x4){0.f, 0.f, 0.f, 0.f};
#pragma unroll
    for (int s = 0; s < 8; ++s) {
      short8 af[4], bfr[4];
#pragma unroll
      for (int t = 0; t < 4; ++t) af[t] = *(const short8*)&As[wm * 64 + t * 16 + l15][s * 32 + quad * 8];
#pragma unroll
      for (int t = 0; t < 4; ++t) bfr[t] = *(const short8*)&Bs[wn * 64 + t * 16 + l15][s * 32 + quad * 8];
#pragma unroll
      for (int i = 0; i < 4; ++i)
#pragma unroll
        for (int j = 0; j < 4; ++j)
          acc[i][j] = __builtin_amdgcn_mfma_f32_16x16x32_bf16(af[i], bfr[j], acc[i][j], 0, 0, 0);
    }
#pragma unroll
    for (int i = 0; i < 4; ++i) {
#pragma unroll
      for (int r = 0; r < 4; ++r) {
        const int c = ch * 128 + wm * 64 + i * 16 + quad * 4 + r;
        const float bc = bias[c];
        const size_t rowbase = ((size_t)b * 256 + c) * 4096 + qb;
#pragma unroll
        for (int j = 0; j < 4; ++j) {
          const int q = wn * 64 + j * 16 + l15;
          OUT[rowbase + q] = acc[i][j][r] + bc + x2[rowbase + q];
        }
      }
    }
    __syncthreads();  // protect As before next-half reload
  }
}

// -----------------------------------------------------------------------------
extern "C" void kernel_launch(void* const* d_in, const int* in_sizes, int n_in,
                              void* d_out, int out_size, void* d_ws, size_t ws_size,
                              hipStream_t stream) {
  const float* x1 = (const float*)d_in[0];
  const float* x2 = (const float*)d_in[1];
  const float* ln1_g = (const float*)d_in[2];
  const float* ln1_b = (const float*)d_in[3];
  const float* ln2_g = (const float*)d_in[4];
  const float* ln2_b = (const float*)d_in[5];
  const float* pos_scale = (const float*)d_in[6];
  const float* W_off = (const float*)d_in[7];
  const float* b_off = (const float*)d_in[8];
  const float* W_att = (const float*)d_in[9];
  const float* b_att = (const float*)d_in[10];
  const float* W_val = (const float*)d_in[11];
  const float* b_val = (const float*)d_in[12];
  const float* W_out = (const float*)d_in[13];
  const float* b_out = (const float*)d_in[14];
  float* out = (float*)d_out;

  char* ws = (char*)d_ws;
  const size_t plane2 = (size_t)kM * kC * sizeof(unsigned short);  // 16 MiB
  unsigned short* Vb   = (unsigned short*)(ws);
  unsigned short* AOb  = (unsigned short*)(ws + plane2);
  float* RAW           = (float*)(ws + 2 * plane2);
  unsigned short* WvT  = (unsigned short*)(ws + 2 * plane2 + (size_t)kM * 48 * 4);
  unsigned short* WoT  = WvT + 65536;
  unsigned short* WoaT = WoT + 65536;

  prep_weights_kernel<<<256, 256, 0, stream>>>(W_val, W_out, W_off, W_att, WvT, WoT, WoaT);
  fused_offatt_kernel<<<kM / 128, 256, 0, stream>>>(x1, ln1_g, ln1_b, pos_scale, WoaT,
                                                    b_off, b_att, RAW);
  fused_val_kernel<<<kM / 128, 256, 0, stream>>>(x2, ln2_g, ln2_b, WvT, b_val, Vb);
  sample_kernel<<<kM / 8, 256, 0, stream>>>(RAW, Vb, AOb);
  gemm_out_kernel<<<kM / 128, 256, 0, stream>>>(WoT, AOb, b_out, x2, out);
}

// Round 5
// 201.612 us; speedup vs baseline: 1.2160x; 1.2160x over previous
//
#include <hip/hip_runtime.h>
#include <math.h>

// (B,C,H,W)=(8,256,64,64); NH=NP=4, d=64, Nq=4096, M=B*Nq=32768.
namespace {
constexpr int kC = 256;
constexpr int kNq = 4096;
constexpr int kM = 32768;
}

typedef __attribute__((ext_vector_type(8))) short short8;
typedef __attribute__((ext_vector_type(4))) float f32x4;

__device__ inline unsigned short f2bf(float f) {
  union { float f; unsigned u; } v; v.f = f;
  unsigned r = (v.u + 0x7FFFu + ((v.u >> 16) & 1u)) >> 16;  // RNE
  return (unsigned short)r;
}
__device__ inline float uasf(unsigned u) {
  union { unsigned u; float f; } v; v.u = u; return v.f;
}

// -----------------------------------------------------------------------------
// K0: weight prep — bf16 + transpose so MFMA operands are row-major in K.
// -----------------------------------------------------------------------------
__global__ __launch_bounds__(256)
void prep_weights_kernel(const float* __restrict__ Wv, const float* __restrict__ Wo,
                         const float* __restrict__ Woff, const float* __restrict__ Watt,
                         unsigned short* __restrict__ WvT, unsigned short* __restrict__ WoT,
                         unsigned short* __restrict__ WoaT) {
  const int i = blockIdx.x * 256 + threadIdx.x;  // 256 blocks -> i < 65536
  {
    const int n = i >> 8, k = i & 255;
    WvT[i] = f2bf(Wv[k * 256 + n]);
    WoT[i] = f2bf(Wo[k * 256 + n]);
  }
  if (i < 16384) {
    const int j = i >> 8, k = i & 255;
    float v = 0.f;
    if (j < 32) v = Woff[k * 32 + j];
    else if (j < 48) v = Watt[k * 16 + (j - 32)];
    WoaT[i] = f2bf(v);
  }
}

// -----------------------------------------------------------------------------
// Fused LN(+qpos)+transpose+GEMM, v2: 64-query tile, 512 blocks, ~70 KB LDS
// -> 2 blocks/CU (round-4 was 104 KB -> 1 block/CU, latency-bound at 10% occ).
// Phase A: 2 groups of 32 q staged through fp32 scratch (float4 global loads),
// per-q mean/rstd, normalized bf16 -> As[64][264]. Phase B: MFMA with A-frags
// from LDS and W-frags streamed directly from global (L2-resident weights).
// Frag layouts [verified r2-r4]: A/B lane = [idx=lane&15][k=quad*8+j];
// C/D: col(l15) = 2nd operand idx, row(quad*4+reg) = 1st operand idx.
// -----------------------------------------------------------------------------

// K1: V = LN2(x2^T) @ W_val + b_val   (bf16 out)
__global__ __launch_bounds__(256)
void fused_val_kernel(const float* __restrict__ X, const float* __restrict__ gam,
                      const float* __restrict__ beta, const unsigned short* __restrict__ Wt,
                      const float* __restrict__ bias, unsigned short* __restrict__ V) {
  __shared__ unsigned short As[64][264];   // 33792 B
  __shared__ float scratch[256][33];       // 33792 B
  __shared__ float psum[8][32];
  __shared__ float psq[8][32];
  __shared__ float smean[64];
  __shared__ float srstd[64];

  const int m0 = blockIdx.x * 64;
  const int b = m0 >> 12;
  const int n0 = m0 & 4095;
  const int tid = threadIdx.x;
  const float gc = gam[tid];
  const float bc = beta[tid];
  const float* Xb = X + (size_t)b * kC * kNq;

  for (int grp = 0; grp < 2; ++grp) {
    float4 vbuf[8];
#pragma unroll
    for (int it = 0; it < 8; ++it) {
      const int i = it * 256 + tid;
      const int c = i >> 3, q4 = (i & 7) * 4;
      vbuf[it] = *(const float4*)&Xb[(size_t)c * kNq + n0 + grp * 32 + q4];
    }
#pragma unroll
    for (int it = 0; it < 8; ++it) {
      const int i = it * 256 + tid;
      const int c = i >> 3, q4 = (i & 7) * 4;
      scratch[c][q4 + 0] = vbuf[it].x;
      scratch[c][q4 + 1] = vbuf[it].y;
      scratch[c][q4 + 2] = vbuf[it].z;
      scratch[c][q4 + 3] = vbuf[it].w;
    }
    __syncthreads();
    {
      const int nn = tid & 31, cg = tid >> 5;
      float s = 0.f, sq = 0.f;
#pragma unroll
      for (int cc = 0; cc < 32; ++cc) {
        const float v = scratch[cg * 32 + cc][nn];
        s += v; sq += v * v;
      }
      psum[cg][nn] = s; psq[cg][nn] = sq;
    }
    __syncthreads();
    if (tid < 32) {
      float S = 0.f, Q = 0.f;
#pragma unroll
      for (int g = 0; g < 8; ++g) { S += psum[g][tid]; Q += psq[g][tid]; }
      const float m = S * (1.f / 256.f);
      const float v = Q * (1.f / 256.f) - m * m;
      smean[grp * 32 + tid] = m;
      srstd[grp * 32 + tid] = rsqrtf(v + 1e-5f);
    }
    __syncthreads();
    for (int q = 0; q < 32; ++q) {
      const int row = grp * 32 + q;
      As[row][tid] = f2bf((scratch[tid][q] - smean[row]) * srstd[row] * gc + bc);
    }
    __syncthreads();
  }

  const int lane = tid & 63, w = tid >> 6;   // wave w -> n-range w*64
  const int l15 = lane & 15, quad = lane >> 4;
  f32x4 acc[4][4];
#pragma unroll
  for (int i = 0; i < 4; ++i)
#pragma unroll
    for (int j = 0; j < 4; ++j) acc[i][j] = (f32x4){0.f, 0.f, 0.f, 0.f};

#pragma unroll
  for (int s = 0; s < 8; ++s) {
    short8 af[4], wf[4];
#pragma unroll
    for (int t = 0; t < 4; ++t) af[t] = *(const short8*)&As[t * 16 + l15][s * 32 + quad * 8];
#pragma unroll
    for (int t = 0; t < 4; ++t)
      wf[t] = *(const short8*)&Wt[(size_t)(w * 64 + t * 16 + l15) * 256 + s * 32 + quad * 8];
#pragma unroll
    for (int i = 0; i < 4; ++i)
#pragma unroll
      for (int j = 0; j < 4; ++j)
        acc[i][j] = __builtin_amdgcn_mfma_f32_16x16x32_bf16(af[i], wf[j], acc[i][j], 0, 0, 0);
  }
#pragma unroll
  for (int i = 0; i < 4; ++i)
#pragma unroll
    for (int j = 0; j < 4; ++j) {
      const int n = w * 64 + j * 16 + l15;
      const float bn = bias[n];
#pragma unroll
      for (int r = 0; r < 4; ++r) {
        const int m = m0 + i * 16 + quad * 4 + r;
        V[(size_t)m * 256 + n] = f2bf(acc[i][j][r] + bn);
      }
    }
}

// K2: RAW = (LN1(x1^T)+qpos) @ [W_off|W_att] + bias  (64q x 48n per block)
__global__ __launch_bounds__(256)
void fused_offatt_kernel(const float* __restrict__ X, const float* __restrict__ gam,
                         const float* __restrict__ beta, const float* __restrict__ ps,
                         const unsigned short* __restrict__ Wt,  // [64][256] WoaT
                         const float* __restrict__ boff, const float* __restrict__ batt,
                         float* __restrict__ RAW) {
  __shared__ unsigned short As[64][264];
  __shared__ float scratch[256][33];
  __shared__ float psum[8][32];
  __shared__ float psq[8][32];
  __shared__ float smean[64];
  __shared__ float srstd[64];

  const int m0 = blockIdx.x * 64;
  const int b = m0 >> 12;
  const int n0 = m0 & 4095;
  const int tid = threadIdx.x;
  const float gc = gam[tid];
  const float bc = beta[tid];
  const float scale = ps[0];
  const int i2 = (tid < 128) ? tid : (tid - 128);
  const float invf = powf(10000.f, -(float)(2 * i2) * (1.f / 256.f));
  const float* Xb = X + (size_t)b * kC * kNq;

  for (int grp = 0; grp < 2; ++grp) {
    float4 vbuf[8];
#pragma unroll
    for (int it = 0; it < 8; ++it) {
      const int i = it * 256 + tid;
      const int c = i >> 3, q4 = (i & 7) * 4;
      vbuf[it] = *(const float4*)&Xb[(size_t)c * kNq + n0 + grp * 32 + q4];
    }
#pragma unroll
    for (int it = 0; it < 8; ++it) {
      const int i = it * 256 + tid;
      const int c = i >> 3, q4 = (i & 7) * 4;
      scratch[c][q4 + 0] = vbuf[it].x;
      scratch[c][q4 + 1] = vbuf[it].y;
      scratch[c][q4 + 2] = vbuf[it].z;
      scratch[c][q4 + 3] = vbuf[it].w;
    }
    __syncthreads();
    {
      const int nn = tid & 31, cg = tid >> 5;
      float s = 0.f, sq = 0.f;
#pragma unroll
      for (int cc = 0; cc < 32; ++cc) {
        const float v = scratch[cg * 32 + cc][nn];
        s += v; sq += v * v;
      }
      psum[cg][nn] = s; psq[cg][nn] = sq;
    }
    __syncthreads();
    if (tid < 32) {
      float S = 0.f, Q = 0.f;
#pragma unroll
      for (int g = 0; g < 8; ++g) { S += psum[g][tid]; Q += psq[g][tid]; }
      const float m = S * (1.f / 256.f);
      const float v = Q * (1.f / 256.f) - m * m;
      smean[grp * 32 + tid] = m;
      srstd[grp * 32 + tid] = rsqrtf(v + 1e-5f);
    }
    __syncthreads();
    for (int q = 0; q < 32; ++q) {
      const int row = grp * 32 + q;
      float val = (scratch[tid][q] - smean[row]) * srstd[row] * gc + bc;
      const float a = (float)(n0 + row) * invf;
      val += ((tid < 128) ? sinf(a) : cosf(a)) * scale;
      As[row][tid] = f2bf(val);
    }
    __syncthreads();
  }

  // GEMM: wave w owns q-frag w (16 q); j-frags 0..2 cover n=0..47 (48..63 dead).
  const int lane = tid & 63, w = tid >> 6;
  const int l15 = lane & 15, quad = lane >> 4;
  f32x4 acc[3];
#pragma unroll
  for (int j = 0; j < 3; ++j) acc[j] = (f32x4){0.f, 0.f, 0.f, 0.f};
#pragma unroll
  for (int s = 0; s < 8; ++s) {
    short8 af = *(const short8*)&As[w * 16 + l15][s * 32 + quad * 8];
    short8 wf[3];
#pragma unroll
    for (int t = 0; t < 3; ++t)
      wf[t] = *(const short8*)&Wt[(size_t)(t * 16 + l15) * 256 + s * 32 + quad * 8];
#pragma unroll
    for (int j = 0; j < 3; ++j)
      acc[j] = __builtin_amdgcn_mfma_f32_16x16x32_bf16(af, wf[j], acc[j], 0, 0, 0);
  }
#pragma unroll
  for (int j = 0; j < 3; ++j) {
    const int n = j * 16 + l15;
    const float bn = (n < 32) ? boff[n] : batt[n - 32];
#pragma unroll
    for (int r = 0; r < 4; ++r) {
      const int m = m0 + w * 16 + quad * 4 + r;
      RAW[(size_t)m * 48 + n] = acc[j][r] + bn;
    }
  }
}

// -----------------------------------------------------------------------------
// K3: two-phase sampling + XCD swizzle (batch = blk&7 -> per-XCD L2 V locality)
// -----------------------------------------------------------------------------
__global__ __launch_bounds__(256)
void sample_kernel(const float* __restrict__ RAW, const unsigned short* __restrict__ V,
                   unsigned short* __restrict__ AO) {
  __shared__ int sidx[128][4];
  __shared__ float swgt[128][4];
  const int blk = blockIdx.x;
  const int m0 = ((blk & 7) * 512 + (blk >> 3)) * 8;
  const int b = m0 >> 12;
  const int tid = threadIdx.x;

  if (tid < 128) {
    const int q_l = tid >> 4, h = (tid >> 2) & 3, p = tid & 3;
    const int m = m0 + q_l;
    const float* raw = RAW + (size_t)m * 48;
    const float l0 = raw[32 + h * 4 + 0];
    const float l1 = raw[32 + h * 4 + 1];
    const float l2 = raw[32 + h * 4 + 2];
    const float l3 = raw[32 + h * 4 + 3];
    const float mx = fmaxf(fmaxf(l0, l1), fmaxf(l2, l3));
    const float e0 = expf(l0 - mx), e1 = expf(l1 - mx), e2 = expf(l2 - mx), e3 = expf(l3 - mx);
    const float lp = (p == 0) ? e0 : (p == 1) ? e1 : (p == 2) ? e2 : e3;
    const float attp = lp / (e0 + e1 + e2 + e3);

    const float ox = raw[h * 8 + p * 2 + 0];
    const float oy = raw[h * 8 + p * 2 + 1];
    const float px = (float)(m & 63) + ox;        // W=64 cancels the normalizer
    const float py = (float)((m >> 6) & 63) + oy;
    const float fx = floorf(px), fy = floorf(py);
    const float wx = px - fx, wy = py - fy;
    const int x0 = (int)fx, y0 = (int)fy;
#pragma unroll
    for (int c = 0; c < 4; ++c) {
      const int dx = c & 1, dy = c >> 1;
      const int xx = x0 + dx, yy = y0 + dy;
      const bool valid = (xx >= 0) & (xx < 64) & (yy >= 0) & (yy < 64);
      const float wc = (dx ? wx : 1.f - wx) * (dy ? wy : 1.f - wy) * attp;
      swgt[tid][c] = valid ? wc : 0.f;
      const int xc = min(max(xx, 0), 63), yc = min(max(yy, 0), 63);
      sidx[tid][c] = yc * 64 + xc;
    }
  }
  __syncthreads();

  const int q_l = tid >> 5, sub = tid & 31;
  const int h = sub >> 3, c8 = (sub & 7) * 8;
  const int trip0 = q_l * 16 + h * 4;
  const unsigned short* vb = V + (size_t)b * kNq * kC + h * 64 + c8;
  float acc[8] = {};
#pragma unroll
  for (int p = 0; p < 4; ++p) {
    const int4 idx = *(const int4*)&sidx[trip0 + p][0];
    const float4 wv = *(const float4*)&swgt[trip0 + p][0];
    const int ia[4] = {idx.x, idx.y, idx.z, idx.w};
    const float wa[4] = {wv.x, wv.y, wv.z, wv.w};
#pragma unroll
    for (int c = 0; c < 4; ++c) {
      const uint4 u = *(const uint4*)&vb[(size_t)ia[c] * kC];
      const float w = wa[c];
      acc[0] = fmaf(w, uasf(u.x << 16), acc[0]);
      acc[1] = fmaf(w, uasf(u.x & 0xffff0000u), acc[1]);
      acc[2] = fmaf(w, uasf(u.y << 16), acc[2]);
      acc[3] = fmaf(w, uasf(u.y & 0xffff0000u), acc[3]);
      acc[4] = fmaf(w, uasf(u.z << 16), acc[4]);
      acc[5] = fmaf(w, uasf(u.z & 0xffff0000u), acc[5]);
      acc[6] = fmaf(w, uasf(u.w << 16), acc[6]);
      acc[7] = fmaf(w, uasf(u.w & 0xffff0000u), acc[7]);
    }
  }
  const int m = m0 + q_l;
  short8 outv;
#pragma unroll
  for (int e = 0; e < 8; ++e) outv[e] = (short)f2bf(acc[e]);
  *(short8*)&AO[(size_t)m * kC + h * 64 + c8] = outv;
}

// -----------------------------------------------------------------------------
// K4: out-projection transposed: D[c][q] = WoT[c][:] . AO[q][:] + bias + x2.
// v2: only the AO tile in LDS (34 KB); W frags streamed from L2 -> 3 blocks/CU.
// -----------------------------------------------------------------------------
__global__ __launch_bounds__(256, 3)
void gemm_out_kernel(const unsigned short* __restrict__ Wt,  // [256][256] WoT
                     const unsigned short* __restrict__ AO,  // [kM][256] bf16
                     const float* __restrict__ bias, const float* __restrict__ x2,
                     float* __restrict__ OUT) {
  __shared__ unsigned short Bs[64][264];  // AO rows (q)
  const int q0 = blockIdx.x * 64;
  const int tid = threadIdx.x;
  const int lane = tid & 63, w = tid >> 6;   // wave w -> c-range w*64
  const int l15 = lane & 15, quad = lane >> 4;

#pragma unroll
  for (int it = 0; it < 8; ++it) {
    const int i = it * 256 + tid;
    const int r = i >> 5, cc = (i & 31) * 8;
    *(short8*)&Bs[r][cc] = *(const short8*)&AO[(size_t)(q0 + r) * 256 + cc];
  }
  __syncthreads();

  f32x4 acc[4][4];
#pragma unroll
  for (int i = 0; i < 4; ++i)
#pragma unroll
    for (int j = 0; j < 4; ++j) acc[i][j] = (f32x4){0.f, 0.f, 0.f, 0.f};

#pragma unroll
  for (int s = 0; s < 8; ++s) {
    short8 wf[4], bf[4];
#pragma unroll
    for (int t = 0; t < 4; ++t)
      wf[t] = *(const short8*)&Wt[(size_t)(w * 64 + t * 16 + l15) * 256 + s * 32 + quad * 8];
#pragma unroll
    for (int t = 0; t < 4; ++t) bf[t] = *(const short8*)&Bs[t * 16 + l15][s * 32 + quad * 8];
#pragma unroll
    for (int i = 0; i < 4; ++i)
#pragma unroll
      for (int j = 0; j < 4; ++j)
        acc[i][j] = __builtin_amdgcn_mfma_f32_16x16x32_bf16(wf[i], bf[j], acc[i][j], 0, 0, 0);
  }

  const int b = q0 >> 12;
  const int qb = q0 & 4095;
#pragma unroll
  for (int i = 0; i < 4; ++i) {
#pragma unroll
    for (int r = 0; r < 4; ++r) {
      const int c = w * 64 + i * 16 + quad * 4 + r;
      const float bc = bias[c];
      const size_t rowbase = ((size_t)b * 256 + c) * 4096 + qb;
#pragma unroll
      for (int j = 0; j < 4; ++j) {
        const int q = j * 16 + l15;
        OUT[rowbase + q] = acc[i][j][r] + bc + x2[rowbase + q];
      }
    }
  }
}

// -----------------------------------------------------------------------------
extern "C" void kernel_launch(void* const* d_in, const int* in_sizes, int n_in,
                              void* d_out, int out_size, void* d_ws, size_t ws_size,
                              hipStream_t stream) {
  const float* x1 = (const float*)d_in[0];
  const float* x2 = (const float*)d_in[1];
  const float* ln1_g = (const float*)d_in[2];
  const float* ln1_b = (const float*)d_in[3];
  const float* ln2_g = (const float*)d_in[4];
  const float* ln2_b = (const float*)d_in[5];
  const float* pos_scale = (const float*)d_in[6];
  const float* W_off = (const float*)d_in[7];
  const float* b_off = (const float*)d_in[8];
  const float* W_att = (const float*)d_in[9];
  const float* b_att = (const float*)d_in[10];
  const float* W_val = (const float*)d_in[11];
  const float* b_val = (const float*)d_in[12];
  const float* W_out = (const float*)d_in[13];
  const float* b_out = (const float*)d_in[14];
  float* out = (float*)d_out;

  char* ws = (char*)d_ws;
  const size_t plane2 = (size_t)kM * kC * sizeof(unsigned short);  // 16 MiB
  unsigned short* Vb   = (unsigned short*)(ws);
  unsigned short* AOb  = (unsigned short*)(ws + plane2);
  float* RAW           = (float*)(ws + 2 * plane2);
  unsigned short* WvT  = (unsigned short*)(ws + 2 * plane2 + (size_t)kM * 48 * 4);
  unsigned short* WoT  = WvT + 65536;
  unsigned short* WoaT = WoT + 65536;

  prep_weights_kernel<<<256, 256, 0, stream>>>(W_val, W_out, W_off, W_att, WvT, WoT, WoaT);
  fused_offatt_kernel<<<kM / 64, 256, 0, stream>>>(x1, ln1_g, ln1_b, pos_scale, WoaT,
                                                   b_off, b_att, RAW);
  fused_val_kernel<<<kM / 64, 256, 0, stream>>>(x2, ln2_g, ln2_b, WvT, b_val, Vb);
  sample_kernel<<<kM / 8, 256, 0, stream>>>(RAW, Vb, AOb);
  gemm_out_kernel<<<kM / 64, 256, 0, stream>>>(WoT, AOb, b_out, x2, out);
}

// Round 6
// 185.005 us; speedup vs baseline: 1.3251x; 1.0898x over previous
//
#include <hip/hip_runtime.h>
#include <math.h>

// (B,C,H,W)=(8,256,64,64); NH=NP=4, d=64, Nq=4096, M=B*Nq=32768.
namespace {
constexpr int kC = 256;
constexpr int kNq = 4096;
constexpr int kM = 32768;
}

typedef __attribute__((ext_vector_type(8))) short short8;
typedef __attribute__((ext_vector_type(4))) float f32x4;

__device__ inline unsigned short f2bf(float f) {
  union { float f; unsigned u; } v; v.f = f;
  unsigned r = (v.u + 0x7FFFu + ((v.u >> 16) & 1u)) >> 16;  // RNE
  return (unsigned short)r;
}
__device__ inline float uasf(unsigned u) {
  union { unsigned u; float f; } v; v.u = u; return v.f;
}

// -----------------------------------------------------------------------------
// K0: weight prep — bf16 + transpose so MFMA operands are row-major in K.
// -----------------------------------------------------------------------------
__global__ __launch_bounds__(256)
void prep_weights_kernel(const float* __restrict__ Wv, const float* __restrict__ Wo,
                         const float* __restrict__ Woff, const float* __restrict__ Watt,
                         unsigned short* __restrict__ WvT, unsigned short* __restrict__ WoT,
                         unsigned short* __restrict__ WoaT) {
  const int i = blockIdx.x * 256 + threadIdx.x;  // 256 blocks -> i < 65536
  {
    const int n = i >> 8, k = i & 255;
    WvT[i] = f2bf(Wv[k * 256 + n]);
    WoT[i] = f2bf(Wo[k * 256 + n]);
  }
  if (i < 16384) {
    const int j = i >> 8, k = i & 255;
    float v = 0.f;
    if (j < 32) v = Woff[k * 32 + j];
    else if (j < 48) v = Watt[k * 16 + (j - 32)];
    WoaT[i] = f2bf(v);
  }
}

// -----------------------------------------------------------------------------
// K1: merged LN(+qpos)+transpose+GEMM. 1024 blocks, mode = blockIdx&1:
//   mode 0: V  = LN2(x2^T) @ W_val + b_val            (bf16 out)
//   mode 1: RAW= (LN1(x1^T)+qpos) @ [W_off|W_att] + b (fp32 out, 48 cols)
// Interleaving both modes in one dispatch doubles resident parallelism so the
// latency-bound phase-A chains overlap. ~70 KB LDS -> 2 blocks/CU (8 waves).
// Frag layouts [verified r2-r5]: A/B lane = [idx=lane&15][k=quad*8+j];
// C/D: col(l15) = 2nd operand idx, row(quad*4+reg) = 1st operand idx.
// -----------------------------------------------------------------------------
__global__ __launch_bounds__(256)
void fused_ln_gemm_kernel(const float* __restrict__ x1, const float* __restrict__ x2,
                          const float* __restrict__ ln1_g, const float* __restrict__ ln1_b,
                          const float* __restrict__ ln2_g, const float* __restrict__ ln2_b,
                          const float* __restrict__ ps,
                          const unsigned short* __restrict__ WvT,
                          const float* __restrict__ b_val, unsigned short* __restrict__ V,
                          const unsigned short* __restrict__ WoaT,
                          const float* __restrict__ boff, const float* __restrict__ batt,
                          float* __restrict__ RAW) {
  __shared__ unsigned short As[64][264];   // 33792 B
  __shared__ float scratch[256][33];       // 33792 B
  __shared__ float psum[8][32];
  __shared__ float psq[8][32];
  __shared__ float smean[64];
  __shared__ float srstd[64];

  const int mode = blockIdx.x & 1;         // 0: val path (x2), 1: offatt (x1)
  const int m0 = (blockIdx.x >> 1) * 64;
  const int b = m0 >> 12;
  const int n0 = m0 & 4095;
  const int tid = threadIdx.x;
  const float* X = mode ? x1 : x2;
  const float gc = mode ? ln1_g[tid] : ln2_g[tid];
  const float bc = mode ? ln1_b[tid] : ln2_b[tid];
  float scale = 0.f, invf = 0.f;
  if (mode) {
    scale = ps[0];
    const int i2 = (tid < 128) ? tid : (tid - 128);
    invf = powf(10000.f, -(float)(2 * i2) * (1.f / 256.f));
  }
  const float* Xb = X + (size_t)b * kC * kNq;

  for (int grp = 0; grp < 2; ++grp) {
    float4 vbuf[8];
#pragma unroll
    for (int it = 0; it < 8; ++it) {
      const int i = it * 256 + tid;
      const int c = i >> 3, q4 = (i & 7) * 4;
      vbuf[it] = *(const float4*)&Xb[(size_t)c * kNq + n0 + grp * 32 + q4];
    }
#pragma unroll
    for (int it = 0; it < 8; ++it) {
      const int i = it * 256 + tid;
      const int c = i >> 3, q4 = (i & 7) * 4;
      scratch[c][q4 + 0] = vbuf[it].x;
      scratch[c][q4 + 1] = vbuf[it].y;
      scratch[c][q4 + 2] = vbuf[it].z;
      scratch[c][q4 + 3] = vbuf[it].w;
    }
    __syncthreads();
    {
      const int nn = tid & 31, cg = tid >> 5;
      float s = 0.f, sq = 0.f;
#pragma unroll
      for (int cc = 0; cc < 32; ++cc) {
        const float v = scratch[cg * 32 + cc][nn];
        s += v; sq += v * v;
      }
      psum[cg][nn] = s; psq[cg][nn] = sq;
    }
    __syncthreads();
    if (tid < 32) {
      float S = 0.f, Q = 0.f;
#pragma unroll
      for (int g = 0; g < 8; ++g) { S += psum[g][tid]; Q += psq[g][tid]; }
      const float m = S * (1.f / 256.f);
      const float v = Q * (1.f / 256.f) - m * m;
      smean[grp * 32 + tid] = m;
      srstd[grp * 32 + tid] = rsqrtf(v + 1e-5f);
    }
    __syncthreads();
    if (mode) {
      for (int q = 0; q < 32; ++q) {
        const int row = grp * 32 + q;
        float val = (scratch[tid][q] - smean[row]) * srstd[row] * gc + bc;
        const float a = (float)(n0 + row) * invf;
        val += ((tid < 128) ? sinf(a) : cosf(a)) * scale;
        As[row][tid] = f2bf(val);
      }
    } else {
      for (int q = 0; q < 32; ++q) {
        const int row = grp * 32 + q;
        As[row][tid] = f2bf((scratch[tid][q] - smean[row]) * srstd[row] * gc + bc);
      }
    }
    __syncthreads();
  }

  const int lane = tid & 63, w = tid >> 6;
  const int l15 = lane & 15, quad = lane >> 4;

  if (mode == 0) {
    // full 64x256 GEMM: wave w -> n-range w*64; W frags streamed from L2
    f32x4 acc[4][4];
#pragma unroll
    for (int i = 0; i < 4; ++i)
#pragma unroll
      for (int j = 0; j < 4; ++j) acc[i][j] = (f32x4){0.f, 0.f, 0.f, 0.f};
#pragma unroll
    for (int s = 0; s < 8; ++s) {
      short8 af[4], wf[4];
#pragma unroll
      for (int t = 0; t < 4; ++t) af[t] = *(const short8*)&As[t * 16 + l15][s * 32 + quad * 8];
#pragma unroll
      for (int t = 0; t < 4; ++t)
        wf[t] = *(const short8*)&WvT[(size_t)(w * 64 + t * 16 + l15) * 256 + s * 32 + quad * 8];
#pragma unroll
      for (int i = 0; i < 4; ++i)
#pragma unroll
        for (int j = 0; j < 4; ++j)
          acc[i][j] = __builtin_amdgcn_mfma_f32_16x16x32_bf16(af[i], wf[j], acc[i][j], 0, 0, 0);
    }
#pragma unroll
    for (int i = 0; i < 4; ++i)
#pragma unroll
      for (int j = 0; j < 4; ++j) {
        const int n = w * 64 + j * 16 + l15;
        const float bn = b_val[n];
#pragma unroll
        for (int r = 0; r < 4; ++r) {
          const int m = m0 + i * 16 + quad * 4 + r;
          V[(size_t)m * 256 + n] = f2bf(acc[i][j][r] + bn);
        }
      }
  } else {
    // 64q x 48n: wave w owns q-frag w; j-frags 0..2 cover n=0..47
    f32x4 acc[3];
#pragma unroll
    for (int j = 0; j < 3; ++j) acc[j] = (f32x4){0.f, 0.f, 0.f, 0.f};
#pragma unroll
    for (int s = 0; s < 8; ++s) {
      short8 af = *(const short8*)&As[w * 16 + l15][s * 32 + quad * 8];
      short8 wf[3];
#pragma unroll
      for (int t = 0; t < 3; ++t)
        wf[t] = *(const short8*)&WoaT[(size_t)(t * 16 + l15) * 256 + s * 32 + quad * 8];
#pragma unroll
      for (int j = 0; j < 3; ++j)
        acc[j] = __builtin_amdgcn_mfma_f32_16x16x32_bf16(af, wf[j], acc[j], 0, 0, 0);
    }
#pragma unroll
    for (int j = 0; j < 3; ++j) {
      const int n = j * 16 + l15;
      const float bn = (n < 32) ? boff[n] : batt[n - 32];
#pragma unroll
      for (int r = 0; r < 4; ++r) {
        const int m = m0 + w * 16 + quad * 4 + r;
        RAW[(size_t)m * 48 + n] = acc[j][r] + bn;
      }
    }
  }
}

// -----------------------------------------------------------------------------
// K2: fused sampling + out-projection + residual. Block = 64 queries of one
// batch (XCD swizzle: batch = blk&7 -> per-XCD L2 V locality). Phases:
//   S1: 1024 (q,h,p) triples -> softmax+bilinear corner idx/wgt in LDS
//   S2: gather from V, accumulate, write AO tile (bf16) DIRECTLY into the
//       MFMA B-operand LDS buffer (no AO HBM round-trip)
//   MFMA: D[c][q] = WoT[c][:] . AO[q][:]  (W frags streamed from L2)
//   Epilogue: stage 128c x 64q fp32 tile in LDS (reusing dead sidx/swgt),
//       then float4 OUT-store + x2 residual (2 rounds of 32 KB).
// LDS: Bs 33.8 KB + 32 KB = 66 KB -> 2 blocks/CU.
// -----------------------------------------------------------------------------
__global__ __launch_bounds__(256)
void sample_out_kernel(const float* __restrict__ RAW, const unsigned short* __restrict__ V,
                       const unsigned short* __restrict__ Wt,  // [256][256] WoT
                       const float* __restrict__ bias, const float* __restrict__ x2,
                       float* __restrict__ OUT) {
  __shared__ unsigned short Bs[64][264];         // AO tile (q x c), 33792 B
  __shared__ __align__(16) char smemA[32768];    // sidx/swgt, then fp32 out tile
  int (*sidx)[4] = (int(*)[4])smemA;             // [1024][4]
  float (*swgt)[4] = (float(*)[4])(smemA + 16384);
  float* ot = (float*)smemA;                     // [128][64] fp32 (epilogue)

  const int blk = blockIdx.x;
  const int b = blk & 7;
  const int tile = blk >> 3;                     // 64 q-tiles per batch
  const int m0 = b * 4096 + tile * 64;
  const int tid = threadIdx.x;

  // ---- S1: corner weights/indices for 64q x 4h x 4p ----
#pragma unroll
  for (int t = 0; t < 4; ++t) {
    const int trip = t * 256 + tid;
    const int q_l = trip >> 4, h = (trip >> 2) & 3, p = trip & 3;
    const int m = m0 + q_l;
    const float* raw = RAW + (size_t)m * 48;
    const float l0 = raw[32 + h * 4 + 0];
    const float l1 = raw[32 + h * 4 + 1];
    const float l2 = raw[32 + h * 4 + 2];
    const float l3 = raw[32 + h * 4 + 3];
    const float mx = fmaxf(fmaxf(l0, l1), fmaxf(l2, l3));
    const float e0 = expf(l0 - mx), e1 = expf(l1 - mx), e2 = expf(l2 - mx), e3 = expf(l3 - mx);
    const float lp = (p == 0) ? e0 : (p == 1) ? e1 : (p == 2) ? e2 : e3;
    const float attp = lp / (e0 + e1 + e2 + e3);

    const float ox = raw[h * 8 + p * 2 + 0];
    const float oy = raw[h * 8 + p * 2 + 1];
    const float px = (float)(m & 63) + ox;       // W=64 cancels the normalizer
    const float py = (float)((m >> 6) & 63) + oy;
    const float fx = floorf(px), fy = floorf(py);
    const float wx = px - fx, wy = py - fy;
    const int x0 = (int)fx, y0 = (int)fy;
#pragma unroll
    for (int c = 0; c < 4; ++c) {
      const int dx = c & 1, dy = c >> 1;
      const int xx = x0 + dx, yy = y0 + dy;
      const bool valid = (xx >= 0) & (xx < 64) & (yy >= 0) & (yy < 64);
      const float wc = (dx ? wx : 1.f - wx) * (dy ? wy : 1.f - wy) * attp;
      swgt[trip][c] = valid ? wc : 0.f;
      const int xc = min(max(xx, 0), 63), yc = min(max(yy, 0), 63);
      sidx[trip][c] = yc * 64 + xc;
    }
  }
  __syncthreads();

  // ---- S2: gather + accumulate -> Bs (bf16) ----
#pragma unroll
  for (int it = 0; it < 8; ++it) {
    const int lin = it * 256 + tid;
    const int q_l = lin >> 5, sub = lin & 31;
    const int h = sub >> 3, c8 = (sub & 7) * 8;
    const int trip0 = q_l * 16 + h * 4;
    const unsigned short* vb = V + (size_t)b * kNq * kC + h * 64 + c8;
    float acc[8] = {};
#pragma unroll
    for (int p = 0; p < 4; ++p) {
      const int4 idx = *(const int4*)&sidx[trip0 + p][0];
      const float4 wv = *(const float4*)&swgt[trip0 + p][0];
      const int ia[4] = {idx.x, idx.y, idx.z, idx.w};
      const float wa[4] = {wv.x, wv.y, wv.z, wv.w};
#pragma unroll
      for (int c = 0; c < 4; ++c) {
        const uint4 u = *(const uint4*)&vb[(size_t)ia[c] * kC];
        const float w = wa[c];
        acc[0] = fmaf(w, uasf(u.x << 16), acc[0]);
        acc[1] = fmaf(w, uasf(u.x & 0xffff0000u), acc[1]);
        acc[2] = fmaf(w, uasf(u.y << 16), acc[2]);
        acc[3] = fmaf(w, uasf(u.y & 0xffff0000u), acc[3]);
        acc[4] = fmaf(w, uasf(u.z << 16), acc[4]);
        acc[5] = fmaf(w, uasf(u.z & 0xffff0000u), acc[5]);
        acc[6] = fmaf(w, uasf(u.w << 16), acc[6]);
        acc[7] = fmaf(w, uasf(u.w & 0xffff0000u), acc[7]);
      }
    }
    short8 outv;
#pragma unroll
    for (int e = 0; e < 8; ++e) outv[e] = (short)f2bf(acc[e]);
    *(short8*)&Bs[q_l][h * 64 + c8] = outv;
  }
  __syncthreads();

  // ---- MFMA: wave w -> c-range w*64 ----
  const int lane = tid & 63, w = tid >> 6;
  const int l15 = lane & 15, quad = lane >> 4;
  f32x4 acc[4][4];
#pragma unroll
  for (int i = 0; i < 4; ++i)
#pragma unroll
    for (int j = 0; j < 4; ++j) acc[i][j] = (f32x4){0.f, 0.f, 0.f, 0.f};
#pragma unroll
  for (int s = 0; s < 8; ++s) {
    short8 wf[4], bf[4];
#pragma unroll
    for (int t = 0; t < 4; ++t)
      wf[t] = *(const short8*)&Wt[(size_t)(w * 64 + t * 16 + l15) * 256 + s * 32 + quad * 8];
#pragma unroll
    for (int t = 0; t < 4; ++t) bf[t] = *(const short8*)&Bs[t * 16 + l15][s * 32 + quad * 8];
#pragma unroll
    for (int i = 0; i < 4; ++i)
#pragma unroll
      for (int j = 0; j < 4; ++j)
        acc[i][j] = __builtin_amdgcn_mfma_f32_16x16x32_bf16(wf[i], bf[j], acc[i][j], 0, 0, 0);
  }

  // ---- Epilogue: LDS-staged transpose -> float4 stores (+bias +x2) ----
  // acc[i][j][r]: c = w*64 + i*16 + quad*4 + r, q = j*16 + l15.
  const int whalf = w >> 1;      // which 128c half this wave's data is in
  const int clbase = (w & 1) * 64;
  for (int ch = 0; ch < 2; ++ch) {
    __syncthreads();             // S1/S2 LDS (or prev round) dead before write
    if (whalf == ch) {
#pragma unroll
      for (int i = 0; i < 4; ++i)
#pragma unroll
        for (int j = 0; j < 4; ++j)
#pragma unroll
          for (int r = 0; r < 4; ++r)
            ot[(clbase + i * 16 + quad * 4 + r) * 64 + j * 16 + l15] = acc[i][j][r];
    }
    __syncthreads();
#pragma unroll
    for (int t = 0; t < 8; ++t) {
      const int lin = t * 256 + tid;
      const int cl = lin >> 4, q4 = (lin & 15) * 4;
      const int c = ch * 128 + cl;
      const size_t rowbase = ((size_t)b * 256 + c) * 4096 + tile * 64;
      const float4 xv = *(const float4*)&x2[rowbase + q4];
      const float bc = bias[c];
      float4 o;
      o.x = ot[cl * 64 + q4 + 0] + bc + xv.x;
      o.y = ot[cl * 64 + q4 + 1] + bc + xv.y;
      o.z = ot[cl * 64 + q4 + 2] + bc + xv.z;
      o.w = ot[cl * 64 + q4 + 3] + bc + xv.w;
      *(float4*)&OUT[rowbase + q4] = o;
    }
  }
}

// -----------------------------------------------------------------------------
extern "C" void kernel_launch(void* const* d_in, const int* in_sizes, int n_in,
                              void* d_out, int out_size, void* d_ws, size_t ws_size,
                              hipStream_t stream) {
  const float* x1 = (const float*)d_in[0];
  const float* x2 = (const float*)d_in[1];
  const float* ln1_g = (const float*)d_in[2];
  const float* ln1_b = (const float*)d_in[3];
  const float* ln2_g = (const float*)d_in[4];
  const float* ln2_b = (const float*)d_in[5];
  const float* pos_scale = (const float*)d_in[6];
  const float* W_off = (const float*)d_in[7];
  const float* b_off = (const float*)d_in[8];
  const float* W_att = (const float*)d_in[9];
  const float* b_att = (const float*)d_in[10];
  const float* W_val = (const float*)d_in[11];
  const float* b_val = (const float*)d_in[12];
  const float* W_out = (const float*)d_in[13];
  const float* b_out = (const float*)d_in[14];
  float* out = (float*)d_out;

  char* ws = (char*)d_ws;
  const size_t plane2 = (size_t)kM * kC * sizeof(unsigned short);  // 16 MiB
  unsigned short* Vb   = (unsigned short*)(ws);
  float* RAW           = (float*)(ws + plane2);
  unsigned short* WvT  = (unsigned short*)(ws + plane2 + (size_t)kM * 48 * 4);
  unsigned short* WoT  = WvT + 65536;
  unsigned short* WoaT = WoT + 65536;

  prep_weights_kernel<<<256, 256, 0, stream>>>(W_val, W_out, W_off, W_att, WvT, WoT, WoaT);
  fused_ln_gemm_kernel<<<1024, 256, 0, stream>>>(x1, x2, ln1_g, ln1_b, ln2_g, ln2_b,
                                                 pos_scale, WvT, b_val, Vb,
                                                 WoaT, b_off, b_att, RAW);
  sample_out_kernel<<<512, 256, 0, stream>>>(RAW, Vb, WoT, b_out, x2, out);
}